// Round 11
// baseline (886.916 us; speedup 1.0000x reference)
//
#include <hip/hip_runtime.h>
#include <stdint.h>

typedef __attribute__((ext_vector_type(8))) short bhalf8;     // 8 bf16 (4 VGPR)
typedef __attribute__((ext_vector_type(16))) float floatx16;  // 32x32 acc
typedef __attribute__((ext_vector_type(4))) float floatx4;
typedef __attribute__((ext_vector_type(2))) float floatx2;

#define BM 256
#define BN 128
#define BK 64
#define BST 72   // B stride (padded)
#define NT 512

constexpr int Mdim = 8192;   // B*S
constexpr int Ndim = 11008;
constexpr int Kdim = 4096;
constexpr int NTILES = Kdim / BK;                        // 64
constexpr size_t XB_BYTES = (size_t)Mdim * Kdim * 2;     // 67,108,864
constexpr size_t WP_BYTES = (size_t)(Kdim / 16) * Ndim * 16;  // 45,088,768

__device__ __forceinline__ unsigned int cvt_pk_bf16(float lo, float hi) {
  unsigned int r;
  asm("v_cvt_pk_bf16_f32 %0, %1, %2" : "=v"(r) : "v"(lo), "v"(hi));
  return r;
}

// ---------------- prep 1: x f32 -> bf16 (validated) ----------------
__global__ __launch_bounds__(256)
void cvt_x_kernel(const float* __restrict__ x, unsigned short* __restrict__ xb) {
  const int nchunk = Mdim * Kdim / 8;
  const int stride = 2048 * 256;
  for (int c = blockIdx.x * 256 + threadIdx.x; c < nchunk; c += stride) {
    const float4 f0 = *(const float4*)(x + (size_t)c * 8);
    const float4 f1 = *(const float4*)(x + (size_t)c * 8 + 4);
    uint4 pk;
    pk.x = cvt_pk_bf16(f0.x, f0.y);
    pk.y = cvt_pk_bf16(f0.z, f0.w);
    pk.z = cvt_pk_bf16(f1.x, f1.y);
    pk.w = cvt_pk_bf16(f1.z, f1.w);
    *(uint4*)(xb + (size_t)c * 8) = pk;
  }
}

// ------- prep 2: (nib - zero) as fp8 e4m3, Wp[K/16][N][16] (validated) -------
__global__ __launch_bounds__(256)
void prep_wp_kernel(const unsigned int* __restrict__ qweight,
                    const unsigned int* __restrict__ qzeros,
                    unsigned char*      __restrict__ wp)
{
  const int tid  = threadIdx.x;
  const int kb16 = blockIdx.x / 43;
  const int n    = (blockIdx.x % 43) * 256 + tid;
  const int g    = kb16 >> 3;
  const unsigned int qz = qzeros[(size_t)g * (Ndim / 8) + (n >> 3)];
  const float zf = (float)((qz >> ((n & 7) * 4)) & 15u);
  unsigned int outw[4];
#pragma unroll
  for (int h = 0; h < 2; ++h) {
    const unsigned int q = qweight[(size_t)(2 * kb16 + h) * Ndim + n];
#pragma unroll
    for (int pj = 0; pj < 2; ++pj) {
      const float f0 = (float)((q >> (16 * pj))      & 15u) - zf;
      const float f1 = (float)((q >> (16 * pj + 4))  & 15u) - zf;
      const float f2 = (float)((q >> (16 * pj + 8))  & 15u) - zf;
      const float f3 = (float)((q >> (16 * pj + 12)) & 15u) - zf;
      int w = __builtin_amdgcn_cvt_pk_fp8_f32(f0, f1, 0, false);
      w     = __builtin_amdgcn_cvt_pk_fp8_f32(f2, f3, w, true);
      outw[2 * h + pj] = (unsigned int)w;
    }
  }
  uint4 o; o.x = outw[0]; o.y = outw[1]; o.z = outw[2]; o.w = outw[3];
  *(uint4*)(wp + ((size_t)kb16 * Ndim + n) * 16) = o;
}

// ---- main: (F) ORDER-PINNED counted-vmcnt B prefetch + (L) 32x32 MFMA ----
__global__ __launch_bounds__(NT, 1)
void qgemm_wp32(const unsigned short* __restrict__ xb,      // bf16 (M,K) in ws
                const unsigned char*  __restrict__ wp,      // fp8 [K/16][N][16]
                const float*          __restrict__ scales,  // f32 (G,N)
                const float*          __restrict__ bias,    // f32 (N)
                float*                __restrict__ out)     // f32 (M,N)
{
  __shared__ unsigned short As[BM * BK];    // 32768 B, linear+XOR (DMA dest)
  __shared__ unsigned short Bs[BN * BST];   // 18432 B, padded

  const int tid  = threadIdx.x;
  const int lane = tid & 63;
  const int wid  = tid >> 6;
  const int wm   = wid >> 1;        // 0..3 (64-row m sub-tile)
  const int wn   = wid & 1;         // 0..1 (64-col n sub-tile)
  const int r31  = lane & 31;
  const int koc  = lane >> 5;       // 0..1 (k-octet half)

  const int nbn = Ndim / BN;                    // 86
  const int nwg = (Mdim / BM) * nbn;            // 2752 (%8==0)
  const int bid = blockIdx.x;
  const int swz = (bid & 7) * (nwg >> 3) + (bid >> 3);
  const int m0  = (swz / nbn) * BM;
  const int n0  = (swz % nbn) * BN;

  // A DMA source: chunk c=i*NT+tid -> row=c>>3, slot=c&7, logical q=slot^(row&7)
  const unsigned short* asrc[4];
#pragma unroll
  for (int i = 0; i < 4; ++i) {
    const int c   = i * NT + tid;
    const int row = c >> 3;
    const int q   = (c & 7) ^ (row & 7);
    asrc[i] = xb + (size_t)(m0 + row) * Kdim + q * 8;
  }

  // B staging: 16 fp8/thread (one 16B chunk at column nn, k-sub kb)
  const int bc = tid & 127;
  const int kb = tid >> 7;                  // 0..3
  const int nn = n0 + bc;
  const unsigned char* wpbase = wp + ((size_t)kb * Ndim + nn) * 16;
  const size_t wstep = (size_t)4 * Ndim * 16;

  floatx16 acc[2][2] = {};

  // prologue: prefetch tile 0's B chunk + scale
  uint4 wv = *(const uint4*)(wpbase);
  float sc = scales[nn];

  for (int t = 0; t < NTILES; ++t) {
    __builtin_amdgcn_s_barrier();   // all reads of tile t-1 complete

    // ---- A: 4x async DMA global->LDS (MUST be oldest in the vmem queue) ----
    const int k0 = t * BK;
#pragma unroll
    for (int i = 0; i < 4; ++i)
      __builtin_amdgcn_global_load_lds(
          (const __attribute__((address_space(1))) void*)(asrc[i] + k0),
          (__attribute__((address_space(3))) void*)(&As[(i * NT + tid) * 8]),
          16, 0, 0);
    // pin issue order: nothing (esp. the prefetch loads) may move above here
    __builtin_amdgcn_sched_barrier(0);

    // ---- (F) prefetch tile t+1 B chunk + scale (now provably AFTER DMAs) ----
    const int tn = (t + 1) & 63;
    const uint4 wv_next = *(const uint4*)(wpbase + (size_t)tn * wstep);
    const float sc_next = scales[(size_t)(tn >> 1) * Ndim + nn];

    // ---- B: decode the ALREADY-LOADED wv -> bf16 -> LDS ----
    {
      const unsigned int vv[4] = { wv.x, wv.y, wv.z, wv.w };
      unsigned int ow[8];
#pragma unroll
      for (int w = 0; w < 4; ++w) {
        const floatx2 p0 = __builtin_amdgcn_cvt_pk_f32_fp8((int)vv[w], false);
        const floatx2 p1 = __builtin_amdgcn_cvt_pk_f32_fp8((int)vv[w], true);
        ow[2 * w]     = cvt_pk_bf16(p0.x * sc, p0.y * sc);
        ow[2 * w + 1] = cvt_pk_bf16(p1.x * sc, p1.y * sc);
      }
      uint4 q0, q1;
      q0.x = ow[0]; q0.y = ow[1]; q0.z = ow[2]; q0.w = ow[3];
      q1.x = ow[4]; q1.y = ow[5]; q1.z = ow[6]; q1.w = ow[7];
      *(uint4*)(&Bs[bc * BST + kb * 16])     = q0;
      *(uint4*)(&Bs[bc * BST + kb * 16 + 8]) = q1;
    }

    // counted drain: queue = [DMA x4 (oldest), wv_next, sc_next] -> vmcnt(2)
    // retires exactly the 4 DMAs; prefetch stays in flight across the MFMAs.
    asm volatile("s_waitcnt vmcnt(2) lgkmcnt(0)" ::: "memory");
    __builtin_amdgcn_s_barrier();
    __builtin_amdgcn_sched_barrier(0);

    // ---- (L) MFMA: 4 k-steps of 32x32x16 (16 MFMA, 16 ds_read_b128) ----
#pragma unroll
    for (int ks = 0; ks < 4; ++ks) {
      const int oct = ks * 2 + koc;          // logical k-octet 0..7
      bhalf8 a[2], b[2];
#pragma unroll
      for (int mi = 0; mi < 2; ++mi) {
        const int row = wm * 64 + mi * 32 + r31;
        a[mi] = *(const bhalf8*)(&As[row * BK + ((oct ^ (row & 7)) << 3)]);
      }
#pragma unroll
      for (int nj = 0; nj < 2; ++nj) {
        const int row = wn * 64 + nj * 32 + r31;
        b[nj] = *(const bhalf8*)(&Bs[row * BST + oct * 8]);
      }
#pragma unroll
      for (int mi = 0; mi < 2; ++mi)
#pragma unroll
        for (int nj = 0; nj < 2; ++nj)
          acc[mi][nj] = __builtin_amdgcn_mfma_f32_32x32x16_bf16(
              a[mi], b[nj], acc[mi][nj], 0, 0, 0);
    }

    // hand prefetch to next iteration
    wv = wv_next;
    sc = sc_next;
  }

  // ---- epilogue: C/D map (m74/m101): col=lane&31, row=(reg&3)+8*(reg>>2)+4*koc ----
#pragma unroll
  for (int nj = 0; nj < 2; ++nj) {
    const int col = n0 + wn * 64 + nj * 32 + r31;
    const float bsv = bias[col];
#pragma unroll
    for (int mi = 0; mi < 2; ++mi) {
      const int rbase = m0 + wm * 64 + mi * 32 + 4 * koc;
#pragma unroll
      for (int reg = 0; reg < 16; ++reg) {
        const int row = rbase + (reg & 3) + 8 * (reg >> 2);
        out[(size_t)row * Ndim + col] = acc[mi][nj][reg] + bsv;
      }
    }
  }
}

// ------- fallback: round-6 validated kernel, fused int4 dequant ------
__global__ __launch_bounds__(NT, 1)
void qgemm_dma(const unsigned short* __restrict__ xb,
               const unsigned int*   __restrict__ qweight,
               const unsigned int*   __restrict__ qzeros,
               const float*          __restrict__ scales,
               const float*          __restrict__ bias,
               float*                __restrict__ out)
{
  __shared__ unsigned short As[BM * BK];
  __shared__ unsigned short Bs[BN * BST];

  const int tid  = threadIdx.x;
  const int lane = tid & 63;
  const int wid  = tid >> 6;
  const int wm   = wid >> 1;
  const int wn   = wid & 1;
  const int fr   = lane & 15;
  const int kh   = lane >> 4;

  const int nbn = Ndim / BN;
  const int nwg = (Mdim / BM) * nbn;
  const int bid = blockIdx.x;
  const int swz = (bid & 7) * (nwg >> 3) + (bid >> 3);
  const int m0  = (swz / nbn) * BM;
  const int n0  = (swz % nbn) * BN;

  const unsigned short* asrc[4];
#pragma unroll
  for (int i = 0; i < 4; ++i) {
    const int c   = i * NT + tid;
    const int row = c >> 3;
    const int q   = (c & 7) ^ (row & 7);
    asrc[i] = xb + (size_t)(m0 + row) * Kdim + q * 8;
  }

  const int bc = tid & 127;
  const int br = tid >> 7;
  const int nn = n0 + bc;

  floatx4 acc[4][4] = {};

  for (int kt = 0; kt < NTILES; ++kt) {
    const int k0 = kt * BK;
    __syncthreads();

#pragma unroll
    for (int i = 0; i < 4; ++i)
      __builtin_amdgcn_global_load_lds(
          (const __attribute__((address_space(1))) void*)(asrc[i] + k0),
          (__attribute__((address_space(3))) void*)(&As[(i * NT + tid) * 8]),
          16, 0, 0);

    const int g = k0 >> 7;
    const float        s  = scales[(size_t)g * Ndim + nn];
    const unsigned int qz = qzeros[(size_t)g * (Ndim / 8) + (nn >> 3)];
    const float        zc = -(float)((qz >> ((nn & 7) * 4)) & 15u) * s;
    unsigned int qv[2];
    qv[0] = qweight[(size_t)(k0 / 8 + br)     * Ndim + nn];
    qv[1] = qweight[(size_t)(k0 / 8 + br + 4) * Ndim + nn];

#pragma unroll
    for (int i = 0; i < 2; ++i) {
      const unsigned int q = qv[i];
      const int r = br + i * 4;
      uint4 pk;
      unsigned int w[4];
#pragma unroll
      for (int j = 0; j < 4; ++j) {
        const float f0 = fmaf((float)((q >> (8 * j))     & 15u), s, zc);
        const float f1 = fmaf((float)((q >> (8 * j + 4)) & 15u), s, zc);
        w[j] = cvt_pk_bf16(f0, f1);
      }
      pk.x = w[0]; pk.y = w[1]; pk.z = w[2]; pk.w = w[3];
      *(uint4*)(&Bs[bc * BST + r * 8]) = pk;
    }
    __syncthreads();

#pragma unroll
    for (int ks = 0; ks < BK / 32; ++ks) {
      const int qa = (((ks * 4 + kh) ^ (fr & 7)) << 3);
      bhalf8 a[4], b[4];
#pragma unroll
      for (int mi = 0; mi < 4; ++mi)
        a[mi] = *(const bhalf8*)(&As[(wm * 64 + mi * 16 + fr) * BK + qa]);
#pragma unroll
      for (int ni = 0; ni < 4; ++ni)
        b[ni] = *(const bhalf8*)(&Bs[(wn * 64 + ni * 16 + fr) * BST + ks * 32 + kh * 8]);
#pragma unroll
      for (int mi = 0; mi < 4; ++mi)
#pragma unroll
        for (int ni = 0; ni < 4; ++ni)
          acc[mi][ni] = __builtin_amdgcn_mfma_f32_16x16x32_bf16(a[mi], b[ni], acc[mi][ni], 0, 0, 0);
    }
  }

#pragma unroll
  for (int ni = 0; ni < 4; ++ni) {
    const int col = n0 + wn * 64 + ni * 16 + fr;
    const float bsv = bias[col];
#pragma unroll
    for (int mi = 0; mi < 4; ++mi) {
      const int rowb = m0 + wm * 64 + mi * 16 + kh * 4;
#pragma unroll
      for (int e = 0; e < 4; ++e)
        out[(size_t)(rowb + e) * Ndim + col] = acc[mi][ni][e] + bsv;
    }
  }
}

extern "C" void kernel_launch(void* const* d_in, const int* in_sizes, int n_in,
                              void* d_out, int out_size, void* d_ws, size_t ws_size,
                              hipStream_t stream) {
  const float*        x       = (const float*)d_in[0];
  const unsigned int* qweight = (const unsigned int*)d_in[1];
  const unsigned int* qzeros  = (const unsigned int*)d_in[2];
  const float*        scales  = (const float*)d_in[3];
  // d_in[4] = g_idx: arange(K)//128, recomputed in-kernel as k>>7
  const float*        bias    = (const float*)d_in[5];
  float*              outp    = (float*)d_out;

  const int nwg = (Mdim / BM) * (Ndim / BN);   // 2752

  if (ws_size >= XB_BYTES + WP_BYTES) {
    unsigned short* xb  = (unsigned short*)d_ws;
    unsigned char*  wpw = (unsigned char*)d_ws + XB_BYTES;
    cvt_x_kernel<<<dim3(2048), dim3(256), 0, stream>>>(x, xb);
    prep_wp_kernel<<<dim3((Kdim / 16) * 43), dim3(256), 0, stream>>>(qweight, qzeros, wpw);
    qgemm_wp32<<<dim3(nwg), dim3(NT), 0, stream>>>(xb, wpw, scales, bias, outp);
  } else {
    unsigned short* xb = (unsigned short*)d_ws;
    cvt_x_kernel<<<dim3(2048), dim3(256), 0, stream>>>(x, xb);
    qgemm_dma<<<dim3(nwg), dim3(NT), 0, stream>>>(xb, qweight, qzeros, scales, bias, outp);
  }
}

// Round 12
// 784.302 us; speedup vs baseline: 1.1308x; 1.1308x over previous
//
#include <hip/hip_runtime.h>
#include <stdint.h>

typedef __attribute__((ext_vector_type(8))) short bhalf8;   // 8 bf16 (4 VGPR)
typedef __attribute__((ext_vector_type(4))) float floatx4;  // 4 f32 acc
typedef __attribute__((ext_vector_type(2))) float floatx2;  // 2 f32

#define BM 256
#define BN 128
#define BK 64
#define BST 72   // B stride (padded)
#define NT 512

constexpr int Mdim = 8192;   // B*S
constexpr int Ndim = 11008;
constexpr int Kdim = 4096;
constexpr int NTILES = Kdim / BK;                        // 64
constexpr size_t XB_BYTES = (size_t)Mdim * Kdim * 2;     // 67,108,864
constexpr size_t WP_BYTES = (size_t)(Kdim / 16) * Ndim * 16;  // 45,088,768

__device__ __forceinline__ unsigned int cvt_pk_bf16(float lo, float hi) {
  unsigned int r;
  asm("v_cvt_pk_bf16_f32 %0, %1, %2" : "=v"(r) : "v"(lo), "v"(hi));
  return r;
}

// ---------------- prep 1: x f32 -> bf16 (validated) ----------------
__global__ __launch_bounds__(256)
void cvt_x_kernel(const float* __restrict__ x, unsigned short* __restrict__ xb) {
  const int nchunk = Mdim * Kdim / 8;
  const int stride = 2048 * 256;
  for (int c = blockIdx.x * 256 + threadIdx.x; c < nchunk; c += stride) {
    const float4 f0 = *(const float4*)(x + (size_t)c * 8);
    const float4 f1 = *(const float4*)(x + (size_t)c * 8 + 4);
    uint4 pk;
    pk.x = cvt_pk_bf16(f0.x, f0.y);
    pk.y = cvt_pk_bf16(f0.z, f0.w);
    pk.z = cvt_pk_bf16(f1.x, f1.y);
    pk.w = cvt_pk_bf16(f1.z, f1.w);
    *(uint4*)(xb + (size_t)c * 8) = pk;
  }
}

// ------- prep 2: (nib - zero) as fp8 e4m3, Wp[K/16][N][16] (validated) -------
__global__ __launch_bounds__(256)
void prep_wp_kernel(const unsigned int* __restrict__ qweight,
                    const unsigned int* __restrict__ qzeros,
                    unsigned char*      __restrict__ wp)
{
  const int tid  = threadIdx.x;
  const int kb16 = blockIdx.x / 43;
  const int n    = (blockIdx.x % 43) * 256 + tid;
  const int g    = kb16 >> 3;
  const unsigned int qz = qzeros[(size_t)g * (Ndim / 8) + (n >> 3)];
  const float zf = (float)((qz >> ((n & 7) * 4)) & 15u);
  unsigned int outw[4];
#pragma unroll
  for (int h = 0; h < 2; ++h) {
    const unsigned int q = qweight[(size_t)(2 * kb16 + h) * Ndim + n];
#pragma unroll
    for (int pj = 0; pj < 2; ++pj) {
      const float f0 = (float)((q >> (16 * pj))      & 15u) - zf;
      const float f1 = (float)((q >> (16 * pj + 4))  & 15u) - zf;
      const float f2 = (float)((q >> (16 * pj + 8))  & 15u) - zf;
      const float f3 = (float)((q >> (16 * pj + 12)) & 15u) - zf;
      int w = __builtin_amdgcn_cvt_pk_fp8_f32(f0, f1, 0, false);
      w     = __builtin_amdgcn_cvt_pk_fp8_f32(f2, f3, w, true);
      outw[2 * h + pj] = (unsigned int)w;
    }
  }
  uint4 o; o.x = outw[0]; o.y = outw[1]; o.z = outw[2]; o.w = outw[3];
  *(uint4*)(wp + ((size_t)kb16 * Ndim + n) * 16) = o;
}

// ---- main: round-9 16x16 compute + (F) order-pinned prefetch, raw barriers ----
__global__ __launch_bounds__(NT, 1)
void qgemm_wp16f(const unsigned short* __restrict__ xb,      // bf16 (M,K) in ws
                 const unsigned char*  __restrict__ wp,      // fp8 [K/16][N][16]
                 const float*          __restrict__ scales,  // f32 (G,N)
                 const float*          __restrict__ bias,    // f32 (N)
                 float*                __restrict__ out)     // f32 (M,N)
{
  __shared__ unsigned short As[BM * BK];    // 32768 B, linear+XOR (DMA dest)
  __shared__ unsigned short Bs[BN * BST];   // 18432 B, padded

  const int tid  = threadIdx.x;
  const int lane = tid & 63;
  const int wid  = tid >> 6;
  const int wm   = wid >> 1;        // 0..3
  const int wn   = wid & 1;         // 0..1
  const int fr   = lane & 15;
  const int kh   = lane >> 4;       // 0..3

  const int nbn = Ndim / BN;                    // 86
  const int nwg = (Mdim / BM) * nbn;            // 2752 (%8==0)
  const int bid = blockIdx.x;
  const int swz = (bid & 7) * (nwg >> 3) + (bid >> 3);
  const int m0  = (swz / nbn) * BM;
  const int n0  = (swz % nbn) * BN;

  // A DMA source: chunk c=i*NT+tid -> row=c>>3, slot=c&7, logical q=slot^(row&7)
  const unsigned short* asrc[4];
#pragma unroll
  for (int i = 0; i < 4; ++i) {
    const int c   = i * NT + tid;
    const int row = c >> 3;
    const int q   = (c & 7) ^ (row & 7);
    asrc[i] = xb + (size_t)(m0 + row) * Kdim + q * 8;
  }

  // B staging: 16 fp8/thread (one 16B chunk at column nn, k-sub kb)
  const int bc = tid & 127;
  const int kb = tid >> 7;                  // 0..3
  const int nn = n0 + bc;
  const unsigned char* wpbase = wp + ((size_t)kb * Ndim + nn) * 16;
  const size_t wstep = (size_t)4 * Ndim * 16;

  floatx4 acc[4][4] = {};

  // prologue: prefetch tile 0's B chunk + scale
  uint4 wv = *(const uint4*)(wpbase);
  float sc = scales[nn];

  for (int t = 0; t < NTILES; ++t) {
    // top barrier: raw (no vmcnt drain -> prefetch stays in flight)
    __builtin_amdgcn_s_barrier();
    __builtin_amdgcn_sched_barrier(0);

    // ---- A: 4x async DMA global->LDS (oldest in the vmem queue) ----
    const int k0 = t * BK;
#pragma unroll
    for (int i = 0; i < 4; ++i)
      __builtin_amdgcn_global_load_lds(
          (const __attribute__((address_space(1))) void*)(asrc[i] + k0),
          (__attribute__((address_space(3))) void*)(&As[(i * NT + tid) * 8]),
          16, 0, 0);
    __builtin_amdgcn_sched_barrier(0);   // pin: prefetch may not hoist above DMAs

    // ---- (F) prefetch tile t+1 B chunk + scale ----
    const int tn = (t + 1) & 63;
    const uint4 wv_next = *(const uint4*)(wpbase + (size_t)tn * wstep);
    const float sc_next = scales[(size_t)(tn >> 1) * Ndim + nn];

    // ---- B: decode the ALREADY-LOADED wv -> bf16 -> LDS ----
    {
      const unsigned int vv[4] = { wv.x, wv.y, wv.z, wv.w };
      unsigned int ow[8];
#pragma unroll
      for (int w = 0; w < 4; ++w) {
        const floatx2 p0 = __builtin_amdgcn_cvt_pk_f32_fp8((int)vv[w], false);
        const floatx2 p1 = __builtin_amdgcn_cvt_pk_f32_fp8((int)vv[w], true);
        ow[2 * w]     = cvt_pk_bf16(p0.x * sc, p0.y * sc);
        ow[2 * w + 1] = cvt_pk_bf16(p1.x * sc, p1.y * sc);
      }
      uint4 q0, q1;
      q0.x = ow[0]; q0.y = ow[1]; q0.z = ow[2]; q0.w = ow[3];
      q1.x = ow[4]; q1.y = ow[5]; q1.z = ow[6]; q1.w = ow[7];
      *(uint4*)(&Bs[bc * BST + kb * 16])     = q0;
      *(uint4*)(&Bs[bc * BST + kb * 16 + 8]) = q1;
    }

    // counted drain: queue = [DMA x4 (oldest), wv_next, sc_next] -> vmcnt(2)
    asm volatile("s_waitcnt vmcnt(2) lgkmcnt(0)" ::: "memory");
    __builtin_amdgcn_s_barrier();
    __builtin_amdgcn_sched_barrier(0);

    // ---- MFMA: 2 k-steps x 16 of 16x16x32 (16 indep acc chains) ----
#pragma unroll
    for (int ks = 0; ks < BK / 32; ++ks) {
      const int qa = (((ks * 4 + kh) ^ (fr & 7)) << 3);   // swizzled A chunk
      bhalf8 a[4], b[4];
#pragma unroll
      for (int mi = 0; mi < 4; ++mi)
        a[mi] = *(const bhalf8*)(&As[(wm * 64 + mi * 16 + fr) * BK + qa]);
#pragma unroll
      for (int ni = 0; ni < 4; ++ni)
        b[ni] = *(const bhalf8*)(&Bs[(wn * 64 + ni * 16 + fr) * BST + ks * 32 + kh * 8]);
#pragma unroll
      for (int mi = 0; mi < 4; ++mi)
#pragma unroll
        for (int ni = 0; ni < 4; ++ni)
          acc[mi][ni] = __builtin_amdgcn_mfma_f32_16x16x32_bf16(a[mi], b[ni], acc[mi][ni], 0, 0, 0);
    }

    wv = wv_next;
    sc = sc_next;
  }

  // ---- epilogue: +bias, store f32 (C/D: col=lane&15, row=kh*4+e) ----
#pragma unroll
  for (int ni = 0; ni < 4; ++ni) {
    const int col = n0 + wn * 64 + ni * 16 + fr;
    const float bsv = bias[col];
#pragma unroll
    for (int mi = 0; mi < 4; ++mi) {
      const int rowb = m0 + wm * 64 + mi * 16 + kh * 4;
#pragma unroll
      for (int e = 0; e < 4; ++e)
        out[(size_t)(rowb + e) * Ndim + col] = acc[mi][ni][e] + bsv;
    }
  }
}

// ------- fallback: round-6 validated kernel, fused int4 dequant ------
__global__ __launch_bounds__(NT, 1)
void qgemm_dma(const unsigned short* __restrict__ xb,
               const unsigned int*   __restrict__ qweight,
               const unsigned int*   __restrict__ qzeros,
               const float*          __restrict__ scales,
               const float*          __restrict__ bias,
               float*                __restrict__ out)
{
  __shared__ unsigned short As[BM * BK];
  __shared__ unsigned short Bs[BN * BST];

  const int tid  = threadIdx.x;
  const int lane = tid & 63;
  const int wid  = tid >> 6;
  const int wm   = wid >> 1;
  const int wn   = wid & 1;
  const int fr   = lane & 15;
  const int kh   = lane >> 4;

  const int nbn = Ndim / BN;
  const int nwg = (Mdim / BM) * nbn;
  const int bid = blockIdx.x;
  const int swz = (bid & 7) * (nwg >> 3) + (bid >> 3);
  const int m0  = (swz / nbn) * BM;
  const int n0  = (swz % nbn) * BN;

  const unsigned short* asrc[4];
#pragma unroll
  for (int i = 0; i < 4; ++i) {
    const int c   = i * NT + tid;
    const int row = c >> 3;
    const int q   = (c & 7) ^ (row & 7);
    asrc[i] = xb + (size_t)(m0 + row) * Kdim + q * 8;
  }

  const int bc = tid & 127;
  const int br = tid >> 7;
  const int nn = n0 + bc;

  floatx4 acc[4][4] = {};

  for (int kt = 0; kt < NTILES; ++kt) {
    const int k0 = kt * BK;
    __syncthreads();

#pragma unroll
    for (int i = 0; i < 4; ++i)
      __builtin_amdgcn_global_load_lds(
          (const __attribute__((address_space(1))) void*)(asrc[i] + k0),
          (__attribute__((address_space(3))) void*)(&As[(i * NT + tid) * 8]),
          16, 0, 0);

    const int g = k0 >> 7;
    const float        s  = scales[(size_t)g * Ndim + nn];
    const unsigned int qz = qzeros[(size_t)g * (Ndim / 8) + (nn >> 3)];
    const float        zc = -(float)((qz >> ((nn & 7) * 4)) & 15u) * s;
    unsigned int qv[2];
    qv[0] = qweight[(size_t)(k0 / 8 + br)     * Ndim + nn];
    qv[1] = qweight[(size_t)(k0 / 8 + br + 4) * Ndim + nn];

#pragma unroll
    for (int i = 0; i < 2; ++i) {
      const unsigned int q = qv[i];
      const int r = br + i * 4;
      uint4 pk;
      unsigned int w[4];
#pragma unroll
      for (int j = 0; j < 4; ++j) {
        const float f0 = fmaf((float)((q >> (8 * j))     & 15u), s, zc);
        const float f1 = fmaf((float)((q >> (8 * j + 4)) & 15u), s, zc);
        w[j] = cvt_pk_bf16(f0, f1);
      }
      pk.x = w[0]; pk.y = w[1]; pk.z = w[2]; pk.w = w[3];
      *(uint4*)(&Bs[bc * BST + r * 8]) = pk;
    }
    __syncthreads();

#pragma unroll
    for (int ks = 0; ks < BK / 32; ++ks) {
      const int qa = (((ks * 4 + kh) ^ (fr & 7)) << 3);
      bhalf8 a[4], b[4];
#pragma unroll
      for (int mi = 0; mi < 4; ++mi)
        a[mi] = *(const bhalf8*)(&As[(wm * 64 + mi * 16 + fr) * BK + qa]);
#pragma unroll
      for (int ni = 0; ni < 4; ++ni)
        b[ni] = *(const bhalf8*)(&Bs[(wn * 64 + ni * 16 + fr) * BST + ks * 32 + kh * 8]);
#pragma unroll
      for (int mi = 0; mi < 4; ++mi)
#pragma unroll
        for (int ni = 0; ni < 4; ++ni)
          acc[mi][ni] = __builtin_amdgcn_mfma_f32_16x16x32_bf16(a[mi], b[ni], acc[mi][ni], 0, 0, 0);
    }
  }

#pragma unroll
  for (int ni = 0; ni < 4; ++ni) {
    const int col = n0 + wn * 64 + ni * 16 + fr;
    const float bsv = bias[col];
#pragma unroll
    for (int mi = 0; mi < 4; ++mi) {
      const int rowb = m0 + wm * 64 + mi * 16 + kh * 4;
#pragma unroll
      for (int e = 0; e < 4; ++e)
        out[(size_t)(rowb + e) * Ndim + col] = acc[mi][ni][e] + bsv;
    }
  }
}

extern "C" void kernel_launch(void* const* d_in, const int* in_sizes, int n_in,
                              void* d_out, int out_size, void* d_ws, size_t ws_size,
                              hipStream_t stream) {
  const float*        x       = (const float*)d_in[0];
  const unsigned int* qweight = (const unsigned int*)d_in[1];
  const unsigned int* qzeros  = (const unsigned int*)d_in[2];
  const float*        scales  = (const float*)d_in[3];
  // d_in[4] = g_idx: arange(K)//128, recomputed in-kernel as k>>7
  const float*        bias    = (const float*)d_in[5];
  float*              outp    = (float*)d_out;

  const int nwg = (Mdim / BM) * (Ndim / BN);   // 2752

  if (ws_size >= XB_BYTES + WP_BYTES) {
    unsigned short* xb  = (unsigned short*)d_ws;
    unsigned char*  wpw = (unsigned char*)d_ws + XB_BYTES;
    cvt_x_kernel<<<dim3(2048), dim3(256), 0, stream>>>(x, xb);
    prep_wp_kernel<<<dim3((Kdim / 16) * 43), dim3(256), 0, stream>>>(qweight, qzeros, wpw);
    qgemm_wp16f<<<dim3(nwg), dim3(NT), 0, stream>>>(xb, wpw, scales, bias, outp);
  } else {
    unsigned short* xb = (unsigned short*)d_ws;
    cvt_x_kernel<<<dim3(2048), dim3(256), 0, stream>>>(x, xb);
    qgemm_dma<<<dim3(nwg), dim3(NT), 0, stream>>>(xb, qweight, qzeros, scales, bias, outp);
  }
}